// Round 1
// baseline (76.970 us; speedup 1.0000x reference)
//
#include <hip/hip_runtime.h>
#include <hip/hip_bf16.h>

typedef __attribute__((ext_vector_type(8))) short short8;
typedef __attribute__((ext_vector_type(4))) float f32x4;

#define BM 128
#define BN 128
#define BK 64
#define LDST 72  // bf16 elems per LDS row: 64 + 8 pad -> 36 dwords, conflict-free b128

static __device__ __forceinline__ unsigned short f2bf(float f) {
    union { __hip_bfloat16 h; unsigned short u; } cv;
    cv.h = __float2bfloat16(f);
    return cv.u;
}

// Build Wbig[m=o*8+k][kk=f*8+j] = sum_i C[i,j,k] * W[i,o,f], cast to bf16.
__global__ __launch_bounds__(256) void build_wbig(const float* __restrict__ W,
                                                  unsigned short* __restrict__ Wbig) {
    __shared__ float C[8][8][8];
    const int t = threadIdx.x;
    for (int i = t; i < 512; i += 256) ((float*)C)[i] = 0.0f;
    __syncthreads();
    if (t == 0) {
        C[0][0][0] = 1.0f;
        for (int i = 1; i < 8; ++i) { C[0][i][i] = 1.0f; C[i][0][i] = 1.0f; C[i][i][0] = -1.0f; }
        const int tr[7][3] = {{1,2,3},{1,4,5},{1,7,6},{2,4,6},{2,5,7},{3,4,7},{3,6,5}};
        for (int q = 0; q < 7; ++q) {
            const int a = tr[q][0], b = tr[q][1], c = tr[q][2];
            const int p[3][3] = {{a,b,c},{b,c,a},{c,a,b}};
            for (int u = 0; u < 3; ++u) {
                C[p[u][0]][p[u][1]][p[u][2]] = 1.0f;
                C[p[u][1]][p[u][0]][p[u][2]] = -1.0f;
            }
        }
    }
    __syncthreads();
    const int e = blockIdx.x * 256 + t;     // 0..262143
    const int m = e >> 9, kk = e & 511;
    const int o = m >> 3, k = m & 7, f = kk >> 3, j = kk & 7;
    float s = 0.0f;
#pragma unroll
    for (int i = 0; i < 8; ++i) s += C[i][j][k] * W[i * 4096 + o * 64 + f];
    Wbig[e] = f2bf(s);
}

// GEMM: Out[N=65536][512] = X[N][512](fp32->bf16) * WbigT + bias
__global__ __launch_bounds__(256) void oct_gemm(const float* __restrict__ X,
                                                const unsigned short* __restrict__ Wbig,
                                                const float* __restrict__ Bias,
                                                float* __restrict__ Out) {
    __shared__ unsigned short As[BM * LDST];
    __shared__ unsigned short Bs[BN * LDST];

    // XCD-chunked swizzle: each XCD gets 64 consecutive n-tiles x all 4 m-tiles,
    // so the 4 blocks sharing an x-tile land on the SAME per-XCD L2.
    const int bid   = blockIdx.x;        // 0..2047
    const int xcd   = bid & 7;
    const int ix    = bid >> 3;          // 0..255
    const int ntile = xcd * 64 + (ix >> 2);
    const int mtile = ix & 3;
    const int rowBase = ntile * BM;
    const int colBase = mtile * BN;

    const int t    = threadIdx.x;
    const int lane = t & 63;
    const int wave = t >> 6;
    const int wr   = wave >> 1, wc = wave & 1;

    f32x4 acc[4][4];
#pragma unroll
    for (int i = 0; i < 4; ++i)
#pragma unroll
        for (int j = 0; j < 4; ++j) acc[i][j] = (f32x4){0.f, 0.f, 0.f, 0.f};

    const int srow = t >> 3;         // 0..31
    const int scol = (t & 7) * 8;    // element col 0..56

    for (int kt = 0; kt < 512; kt += BK) {
        // stage A: 128x64 fp32 -> bf16 (reg-staged, padded LDS rows)
#pragma unroll
        for (int l = 0; l < 4; ++l) {
            const int r = l * 32 + srow;
            const float* src = X + (size_t)(rowBase + r) * 512 + kt + scol;
            f32x4 v0 = *reinterpret_cast<const f32x4*>(src);
            f32x4 v1 = *reinterpret_cast<const f32x4*>(src + 4);
            short8 p;
            p[0] = (short)f2bf(v0[0]); p[1] = (short)f2bf(v0[1]);
            p[2] = (short)f2bf(v0[2]); p[3] = (short)f2bf(v0[3]);
            p[4] = (short)f2bf(v1[0]); p[5] = (short)f2bf(v1[1]);
            p[6] = (short)f2bf(v1[2]); p[7] = (short)f2bf(v1[3]);
            *reinterpret_cast<short8*>(&As[r * LDST + scol]) = p;
        }
        // stage B: 128x64 bf16 from Wbig (row-major [M][K])
#pragma unroll
        for (int l = 0; l < 4; ++l) {
            const int r = l * 32 + srow;
            short8 v = *reinterpret_cast<const short8*>(Wbig + (size_t)(colBase + r) * 512 + kt + scol);
            *reinterpret_cast<short8*>(&Bs[r * LDST + scol]) = v;
        }
        __syncthreads();

#pragma unroll
        for (int kk = 0; kk < 2; ++kk) {
            const int kb = kk * 32 + (lane >> 4) * 8;
            short8 a[4], b[4];
#pragma unroll
            for (int mi = 0; mi < 4; ++mi)
                a[mi] = *reinterpret_cast<const short8*>(&As[(wr * 64 + mi * 16 + (lane & 15)) * LDST + kb]);
#pragma unroll
            for (int ni = 0; ni < 4; ++ni)
                b[ni] = *reinterpret_cast<const short8*>(&Bs[(wc * 64 + ni * 16 + (lane & 15)) * LDST + kb]);
#pragma unroll
            for (int mi = 0; mi < 4; ++mi)
#pragma unroll
                for (int ni = 0; ni < 4; ++ni)
                    acc[mi][ni] = __builtin_amdgcn_mfma_f32_16x16x32_bf16(a[mi], b[ni], acc[mi][ni], 0, 0, 0);
        }
        __syncthreads();
    }

    // epilogue: +bias, store fp32. D layout: col = lane&15, row = (lane>>4)*4 + reg.
    float bv[4];
#pragma unroll
    for (int ni = 0; ni < 4; ++ni) bv[ni] = Bias[colBase + wc * 64 + ni * 16 + (lane & 15)];
#pragma unroll
    for (int mi = 0; mi < 4; ++mi) {
        const int row0 = rowBase + wr * 64 + mi * 16 + (lane >> 4) * 4;
#pragma unroll
        for (int ni = 0; ni < 4; ++ni) {
            const int col = colBase + wc * 64 + ni * 16 + (lane & 15);
#pragma unroll
            for (int r = 0; r < 4; ++r)
                Out[(size_t)(row0 + r) * 512 + col] = acc[mi][ni][r] + bv[ni];
        }
    }
}

extern "C" void kernel_launch(void* const* d_in, const int* in_sizes, int n_in,
                              void* d_out, int out_size, void* d_ws, size_t ws_size,
                              hipStream_t stream) {
    const float* x = (const float*)d_in[0];   // [65536][512]
    const float* W = (const float*)d_in[1];   // [8][64][64]
    const float* b = (const float*)d_in[2];   // [512]
    float* out = (float*)d_out;               // [65536][512]
    unsigned short* Wbig = (unsigned short*)d_ws;  // 512*512 bf16 = 512 KB

    build_wbig<<<1024, 256, 0, stream>>>(W, Wbig);
    oct_gemm<<<2048, 256, 0, stream>>>(x, Wbig, b, out);
}